// Round 2
// baseline (3834.867 us; speedup 1.0000x reference)
//
#include <hip/hip_runtime.h>

// Path signature M=4, d=10, L=256, B=2048.
// Thread owns (batch b, pair (i,j), k-half h): state s3[5], s4[5][10], plus s1,s2.
// h = tid&1 -> both halves execute identical code (h only enters LDS address math).
// Recurrence per increment v (OLD values on RHS):
//   b_ = v_i v_j/24 + S1_i v_j/6 + S2_ij/2 ; a_ = v_i v_j/6 + S1_i v_j/2 + S2_ij
//   c_k = b_*v_k + S3_k ; S3_k += a_*v_k ; S4_kl += c_k*v_l ; S2 += v_j(v_i/2+S1) ; S1 += v_i
// Grid: 1280 blocks x 320 threads = 409600 threads = 6400 waves = exactly 25 waves/CU
// -> single residency round IFF VGPR <= 73 (hence __launch_bounds__(320,7)).

#define D      10
#define LPATH  256
#define NSTEP  255
#define SIGTOT 11110
#define TB     320
#define SLOTS  3
#define SLOTF  (NSTEP * D)   // 2550 floats of increments per batch

__global__ __launch_bounds__(TB, 7)
void sig_kernel(const float* __restrict__ x, float* __restrict__ out, int B) {
    __shared__ float vlds[SLOTS * SLOTF];   // 30600 B
    const int tid = threadIdx.x;
    const int blk = blockIdx.x;
    const int q0  = blk * (TB / 2);         // first pair index of this block
    const int b0  = q0 / 100;               // first batch touched

    // stage increments v[t][q] = x[t+1][q]-x[t][q] for up to 3 batches (coalesced)
    for (int e = tid; e < SLOTS * SLOTF; e += TB) {
        const int s  = e / SLOTF;
        const int r  = e - s * SLOTF;
        const int bb = b0 + s;
        float v = 0.f;
        if (bb < B) {
            const float* bx = x + (size_t)bb * (LPATH * D);
            v = bx[r + D] - bx[r];
        }
        vlds[e] = v;
    }
    __syncthreads();

    const int g = blk * TB + tid;
    const int q = g >> 1;                   // pair index
    const int h = g & 1;                    // k-half: k in [5h, 5h+5)
    const int b = q / 100;
    const int p = q - b * 100;
    const int i = p / 10;
    const int j = p - i * 10;
    const float* vrow = vlds + (b - b0) * SLOTF;

    float s1 = 0.f, s2 = 0.f;
    float s3[5], s4[50];
    #pragma unroll
    for (int k = 0; k < 5; ++k) s3[k] = 0.f;
    #pragma unroll
    for (int k = 0; k < 50; ++k) s4[k] = 0.f;

    for (int t = 0; t < NSTEP; ++t) {
        const float* row = vrow + t * D;
        const float vi = row[i];            // ds_read, broadcast-ish
        const float vj = row[j];
        const float b_ = vj * (vi * (1.f/24.f) + s1 * (1.f/6.f)) + s2 * 0.5f;
        const float a_ = vj * (vi * (1.f/6.f)  + s1 * 0.5f)      + s2;
        float c[5];
        #pragma unroll
        for (int k = 0; k < 5; ++k) {
            const float vk = row[5 * h + k];   // h in ADDRESS only (no reg indexing)
            c[k] = b_ * vk + s3[k];            // old s3
            s3[k] += a_ * vk;
        }
        #pragma unroll
        for (int lp = 0; lp < 5; ++lp) {
            const float2 v2 = *(const float2*)(row + 2 * lp);  // 8B-aligned
            #pragma unroll
            for (int k = 0; k < 5; ++k) {
                s4[k * 10 + 2 * lp]     += c[k] * v2.x;
                s4[k * 10 + 2 * lp + 1] += c[k] * v2.y;
            }
        }
        s2 += vj * (vi * 0.5f + s1);        // old s1
        s1 += vi;
    }

    // epilogue: [S1(10) | S2(100) | S3(1000) | S4(10000)] per batch
    const size_t ob = (size_t)b * SIGTOT;
    if (h == 0) {
        if (j == 0) out[ob + i] = s1;
        out[ob + 10 + p] = s2;
    }
    float* o3 = out + ob + 110 + (size_t)p * 10 + 5 * h;
    #pragma unroll
    for (int k = 0; k < 5; ++k) o3[k] = s3[k];
    float* o4 = out + ob + 1110 + (size_t)p * 100 + (size_t)(5 * h) * 10;
    #pragma unroll
    for (int k = 0; k < 5; ++k) {
        #pragma unroll
        for (int lp = 0; lp < 5; ++lp) {
            *(float2*)(o4 + k * 10 + 2 * lp) =
                make_float2(s4[k * 10 + 2 * lp], s4[k * 10 + 2 * lp + 1]);
        }
    }
}

extern "C" void kernel_launch(void* const* d_in, const int* in_sizes, int n_in,
                              void* d_out, int out_size, void* d_ws, size_t ws_size,
                              hipStream_t stream) {
    const float* x = (const float*)d_in[0];
    float* out = (float*)d_out;
    const int B = in_sizes[0] / (LPATH * D);        // 2048
    const int nthreads = B * 100 * 2;               // 409600
    const int nblocks = (nthreads + TB - 1) / TB;   // 1280
    sig_kernel<<<nblocks, TB, 0, stream>>>(x, out, B);
}

// Round 3
// 1997.845 us; speedup vs baseline: 1.9195x; 1.9195x over previous
//
#include <hip/hip_runtime.h>

// Path signature M=4, d=10, L=256, B=2048.
// Thread owns (batch b, pair (i,j), k-half h): s1,s2, s3[5], s4[5][10].
// h = g&1 enters ONLY address math (no runtime register indexing -> no scratch).
// Recurrence per increment v (OLD values on RHS):
//   b_ = v_i v_j/24 + S1 v_j/6 + S2/2 ; a_ = v_i v_j/6 + S1 v_j/2 + S2
//   c_k = b_*v_k + S3_k ; S3_k += a_*v_k ; S4_kl += c_k*v_l ; S2 += v_j(v_i/2+S1) ; S1 += v_i
// 256-thread blocks = 128 pairs; increments pre-staged in LDS (<=3 batch slots).
// __launch_bounds__(256,5): VGPR cap 102 (state ~80 fits, NO spill — round-2's
// cap of 73 forced a catastrophic scratch spill). 5 blocks/CU = 20 waves/CU.

#define D      10
#define LPATH  256
#define NSTEP  255
#define SIGTOT 11110
#define TB     256
#define SLOTS  3
#define SLOTF  (NSTEP * D)   // 2550 floats of increments per batch

__global__ __launch_bounds__(TB, 5)
void sig_kernel(const float* __restrict__ x, float* __restrict__ out, int B) {
    __shared__ float vlds[SLOTS * SLOTF];   // 30600 B
    const int tid = threadIdx.x;
    const int blk = blockIdx.x;
    const int q0  = blk * (TB / 2);          // first pair index of this block
    const int b0  = q0 / 100;                // first batch touched
    const int bL  = (q0 + TB / 2 - 1) / 100; // last batch touched
    const int nslot = bL - b0 + 1;           // 2 or 3

    // stage increments v[t][dim] for the touched batches (coalesced)
    for (int e = tid; e < nslot * SLOTF; e += TB) {
        const int s  = e / SLOTF;
        const int r  = e - s * SLOTF;
        const int bb = b0 + s;
        float v = 0.f;
        if (bb < B) {
            const float* bx = x + (size_t)bb * (LPATH * D);
            v = bx[r + D] - bx[r];
        }
        vlds[e] = v;
    }
    __syncthreads();

    const int g = blk * TB + tid;
    const int q = g >> 1;                   // pair index
    const int h = g & 1;                    // k-half: k in [5h, 5h+5)
    const int b = q / 100;
    const int p = q - b * 100;
    const int i = p / 10;
    const int j = p - i * 10;
    const float* vrow = vlds + (b - b0) * SLOTF;

    float s1 = 0.f, s2 = 0.f;
    float s3[5], s4[50];
    #pragma unroll
    for (int k = 0; k < 5; ++k) s3[k] = 0.f;
    #pragma unroll
    for (int k = 0; k < 50; ++k) s4[k] = 0.f;

    for (int t = 0; t < NSTEP; ++t) {
        const float* row = vrow + t * D;
        const float vi = row[i];            // ds_read (runtime lane index -> LDS only)
        const float vj = row[j];
        const float b_ = vj * (vi * (1.f/24.f) + s1 * (1.f/6.f)) + s2 * 0.5f;
        const float a_ = vj * (vi * (1.f/6.f)  + s1 * 0.5f)      + s2;
        float c[5];
        #pragma unroll
        for (int k = 0; k < 5; ++k) {
            const float vk = row[5 * h + k];   // h in ADDRESS only
            c[k] = b_ * vk + s3[k];            // old s3
            s3[k] += a_ * vk;
        }
        #pragma unroll
        for (int lp = 0; lp < 5; ++lp) {
            const float2 v2 = *(const float2*)(row + 2 * lp);  // 8B-aligned
            #pragma unroll
            for (int k = 0; k < 5; ++k) {
                s4[k * 10 + 2 * lp]     += c[k] * v2.x;
                s4[k * 10 + 2 * lp + 1] += c[k] * v2.y;
            }
        }
        s2 += vj * (vi * 0.5f + s1);        // old s1
        s1 += vi;
    }

    // epilogue: [S1(10) | S2(100) | S3(1000) | S4(10000)] per batch
    const size_t ob = (size_t)b * SIGTOT;
    if (h == 0) {
        if (j == 0) out[ob + i] = s1;
        out[ob + 10 + p] = s2;
    }
    float* o3 = out + ob + 110 + (size_t)p * 10 + 5 * h;
    #pragma unroll
    for (int k = 0; k < 5; ++k) o3[k] = s3[k];
    float* o4 = out + ob + 1110 + (size_t)p * 100 + (size_t)(5 * h) * 10;
    #pragma unroll
    for (int k = 0; k < 5; ++k) {
        #pragma unroll
        for (int lp = 0; lp < 5; ++lp) {
            *(float2*)(o4 + k * 10 + 2 * lp) =
                make_float2(s4[k * 10 + 2 * lp], s4[k * 10 + 2 * lp + 1]);
        }
    }
}

extern "C" void kernel_launch(void* const* d_in, const int* in_sizes, int n_in,
                              void* d_out, int out_size, void* d_ws, size_t ws_size,
                              hipStream_t stream) {
    const float* x = (const float*)d_in[0];
    float* out = (float*)d_out;
    const int B = in_sizes[0] / (LPATH * D);        // 2048
    const int nthreads = B * 100 * 2;               // 409600
    const int nblocks = nthreads / TB;              // 1600
    sig_kernel<<<nblocks, TB, 0, stream>>>(x, out, B);
}

// Round 4
// 210.835 us; speedup vs baseline: 18.1890x; 9.4759x over previous
//
#include <hip/hip_runtime.h>

// Path signature M=4, d=10, L=256, B=2048.
// Thread owns (batch b, pair (i,j), k-half h): s1,s2, s3[5], s4[5][10] (~85 live regs).
// h enters ONLY address math -> no runtime register indexing -> no scratch.
// Recurrence per increment v (OLD values on RHS):
//   b_ = v_i v_j/24 + S1 v_j/6 + S2/2 ; a_ = v_i v_j/6 + S1 v_j/2 + S2
//   c_k = b_*v_k + S3_k ; S3_k += a_*v_k ; S4_kl += c_k*v_l ; S2 += v_j(v_i/2+S1) ; S1 += v_i
// __launch_bounds__(256,3): VGPR cap 170 (round 2 cap 73 and round 3 cap 102 both
// forced catastrophic scratch spills; need ~85 + generous headroom). launch_bounds
// is only a CAP — if allocation lands <=102, runtime occupancy is still 5 waves/SIMD.

#define D      10
#define LPATH  256
#define NSTEP  255
#define SIGTOT 11110
#define TB     256
#define SLOTS  3
#define SLOTF  (NSTEP * D)   // 2550 floats of increments per batch

__global__ __launch_bounds__(TB, 3)
void sig_kernel(const float* __restrict__ x, float* __restrict__ out, int B) {
    __shared__ float vlds[SLOTS * SLOTF];   // 30600 B
    const int tid = threadIdx.x;
    const int blk = blockIdx.x;
    const int q0  = blk * (TB / 2);          // first pair index of this block
    const int b0  = q0 / 100;                // first batch touched
    const int bL  = (q0 + TB / 2 - 1) / 100; // last batch touched
    const int nslot = bL - b0 + 1;           // 2 or 3

    // stage increments v[t][dim] for the touched batches (coalesced)
    for (int e = tid; e < nslot * SLOTF; e += TB) {
        const int s  = e / SLOTF;
        const int r  = e - s * SLOTF;
        const int bb = b0 + s;
        float v = 0.f;
        if (bb < B) {
            const float* bx = x + (size_t)bb * (LPATH * D);
            v = bx[r + D] - bx[r];
        }
        vlds[e] = v;
    }
    __syncthreads();

    const int g = blk * TB + tid;
    const int q = g >> 1;                   // pair index
    const int h = g & 1;                    // k-half: k in [5h, 5h+5)
    const int b = q / 100;
    const int p = q - b * 100;
    const int i = p / 10;
    const int j = p - i * 10;
    const float* vrow = vlds + (b - b0) * SLOTF;

    float s1 = 0.f, s2 = 0.f;
    float s3[5], s4[50];
    #pragma unroll
    for (int k = 0; k < 5; ++k) s3[k] = 0.f;
    #pragma unroll
    for (int k = 0; k < 50; ++k) s4[k] = 0.f;

    #pragma unroll 1
    for (int t = 0; t < NSTEP; ++t) {
        const float* row = vrow + t * D;
        const float vi = row[i];            // ds_read (runtime index -> LDS only)
        const float vj = row[j];
        const float b_ = vj * (vi * (1.f/24.f) + s1 * (1.f/6.f)) + s2 * 0.5f;
        const float a_ = vj * (vi * (1.f/6.f)  + s1 * 0.5f)      + s2;
        float c[5];
        #pragma unroll
        for (int k = 0; k < 5; ++k) {
            const float vk = row[5 * h + k];   // h in ADDRESS only
            c[k] = b_ * vk + s3[k];            // old s3
            s3[k] += a_ * vk;
        }
        #pragma unroll
        for (int lp = 0; lp < 5; ++lp) {
            const float2 v2 = *(const float2*)(row + 2 * lp);  // same-addr broadcast
            #pragma unroll
            for (int k = 0; k < 5; ++k) {
                s4[k * 10 + 2 * lp]     += c[k] * v2.x;
                s4[k * 10 + 2 * lp + 1] += c[k] * v2.y;
            }
        }
        s2 += vj * (vi * 0.5f + s1);        // old s1
        s1 += vi;
    }

    // epilogue: [S1(10) | S2(100) | S3(1000) | S4(10000)] per batch
    const size_t ob = (size_t)b * SIGTOT;
    if (h == 0) {
        if (j == 0) out[ob + i] = s1;
        out[ob + 10 + p] = s2;
    }
    float* o3 = out + ob + 110 + (size_t)p * 10 + 5 * h;
    #pragma unroll
    for (int k = 0; k < 5; ++k) o3[k] = s3[k];
    float* o4 = out + ob + 1110 + (size_t)p * 100 + (size_t)(5 * h) * 10;
    #pragma unroll
    for (int k = 0; k < 5; ++k) {
        #pragma unroll
        for (int lp = 0; lp < 5; ++lp) {
            *(float2*)(o4 + k * 10 + 2 * lp) =
                make_float2(s4[k * 10 + 2 * lp], s4[k * 10 + 2 * lp + 1]);
        }
    }
}

extern "C" void kernel_launch(void* const* d_in, const int* in_sizes, int n_in,
                              void* d_out, int out_size, void* d_ws, size_t ws_size,
                              hipStream_t stream) {
    const float* x = (const float*)d_in[0];
    float* out = (float*)d_out;
    const int B = in_sizes[0] / (LPATH * D);        // 2048
    const int nthreads = B * 100 * 2;               // 409600
    const int nblocks = nthreads / TB;              // 1600
    sig_kernel<<<nblocks, TB, 0, stream>>>(x, out, B);
}

// Round 5
// 208.623 us; speedup vs baseline: 18.3818x; 1.0106x over previous
//
#include <hip/hip_runtime.h>

// Path signature M=4, d=10, L=256, B=2048.
// Thread owns (batch b, pair (i,j), k-half h): s1,s2, s3[5], s4[5][10].
// h is WAVE-UNIFORM (h = wave_id & 1): k-half selection compiles to an
// s_cbranch into two template<K0> copies — no divergence, no runtime reg idx.
// Increment row v[0..9] loaded to registers once per step (5x ds_read_b64,
// 8B-aligned: row stride 40B); only v_i, v_j stay as LDS scalar reads.
// Recurrence per step (OLD values on RHS):
//   b_ = v_i v_j/24 + S1 v_j/6 + S2/2 ; a_ = v_i v_j/6 + S1 v_j/2 + S2
//   c_k = b_*v_k + S3_k ; S3_k += a_*v_k ; S4_kl += c_k*v_l
//   S2 += v_j(v_i/2+S1) ; S1 += v_i
// __launch_bounds__(256,3): cap 170 — the only proven non-spilling config
// (caps 73 and 102 both scratch-spilled the ~85-float live state).

#define D      10
#define LPATH  256
#define NSTEP  255
#define SIGTOT 11110
#define TB     256
#define SLOTS  3
#define SLOTF  (NSTEP * D)   // 2550 floats of increments per batch

template<int K0>
__device__ __forceinline__ void run_steps(const float* __restrict__ vrow,
                                          int i, int j,
                                          float& s1, float& s2,
                                          float (&s3)[5], float (&s4)[50]) {
    #pragma unroll 1
    for (int t = 0; t < NSTEP; ++t) {
        const float* row = vrow + t * D;
        float v[D];
        #pragma unroll
        for (int u = 0; u < 5; ++u)
            *(float2*)(v + 2 * u) = *(const float2*)(row + 2 * u);
        const float vi = row[i];            // LDS scalar read (broadcast-ish)
        const float vj = row[j];
        const float b_ = vj * (vi * (1.f/24.f) + s1 * (1.f/6.f)) + s2 * 0.5f;
        const float a_ = vj * (vi * (1.f/6.f)  + s1 * 0.5f)      + s2;
        s2 += vj * fmaf(vi, 0.5f, s1);      // old s1
        s1 += vi;
        float c[5];
        #pragma unroll
        for (int k = 0; k < 5; ++k) {
            const float vk = v[K0 + k];     // compile-time index
            c[k] = fmaf(b_, vk, s3[k]);     // old s3
            s3[k] = fmaf(a_, vk, s3[k]);
        }
        #pragma unroll
        for (int k = 0; k < 5; ++k) {
            #pragma unroll
            for (int l = 0; l < D; ++l)
                s4[k * 10 + l] = fmaf(c[k], v[l], s4[k * 10 + l]);
        }
    }
}

__global__ __launch_bounds__(TB, 3)
void sig_kernel(const float* __restrict__ x, float* __restrict__ out, int B) {
    __shared__ float vlds[SLOTS * SLOTF];   // 30600 B
    const int tid = threadIdx.x;
    const int blk = blockIdx.x;
    const int q0  = blk * (TB / 2);          // first pair index of this block
    const int b0  = q0 / 100;                // first batch touched
    const int bL  = (q0 + TB / 2 - 1) / 100; // last batch touched
    const int nslot = bL - b0 + 1;           // 2 or 3

    // stage increments v[t][dim] for the touched batches (coalesced)
    for (int e = tid; e < nslot * SLOTF; e += TB) {
        const int s  = e / SLOTF;
        const int r  = e - s * SLOTF;
        const int bb = b0 + s;
        float v = 0.f;
        if (bb < B) {
            const float* bx = x + (size_t)bb * (LPATH * D);
            v = bx[r + D] - bx[r];
        }
        vlds[e] = v;
    }
    __syncthreads();

    // wave-uniform half assignment: global wave w -> h = w&1; lane carries pair
    const int wg   = blk * (TB / 64) + (tid >> 6);   // global wave id
    const int lane = tid & 63;
    const int h    = wg & 1;                          // wave-uniform
    const int q    = (wg >> 1) * 64 + lane;           // pair index
    const int b    = q / 100;
    const int p    = q - b * 100;
    const int i    = p / 10;
    const int j    = p - i * 10;
    const float* vrow = vlds + (b - b0) * SLOTF;

    float s1 = 0.f, s2 = 0.f;
    float s3[5], s4[50];
    #pragma unroll
    for (int k = 0; k < 5; ++k) s3[k] = 0.f;
    #pragma unroll
    for (int k = 0; k < 50; ++k) s4[k] = 0.f;

    if (h == 0) run_steps<0>(vrow, i, j, s1, s2, s3, s4);
    else        run_steps<5>(vrow, i, j, s1, s2, s3, s4);

    // epilogue: [S1(10) | S2(100) | S3(1000) | S4(10000)] per batch
    const size_t ob = (size_t)b * SIGTOT;
    const int K0 = 5 * h;
    if (h == 0) {
        if (j == 0) out[ob + i] = s1;
        out[ob + 10 + p] = s2;
    }
    float* o3 = out + ob + 110 + (size_t)p * 10 + K0;
    #pragma unroll
    for (int k = 0; k < 5; ++k) o3[k] = s3[k];
    float* o4 = out + ob + 1110 + (size_t)p * 100 + (size_t)K0 * 10;
    #pragma unroll
    for (int k = 0; k < 5; ++k) {
        #pragma unroll
        for (int lp = 0; lp < 5; ++lp) {
            *(float2*)(o4 + k * 10 + 2 * lp) =
                make_float2(s4[k * 10 + 2 * lp], s4[k * 10 + 2 * lp + 1]);
        }
    }
}

extern "C" void kernel_launch(void* const* d_in, const int* in_sizes, int n_in,
                              void* d_out, int out_size, void* d_ws, size_t ws_size,
                              hipStream_t stream) {
    const float* x = (const float*)d_in[0];
    float* out = (float*)d_out;
    const int B = in_sizes[0] / (LPATH * D);        // 2048
    const int nthreads = B * 100 * 2;               // 409600
    const int nblocks = nthreads / TB;              // 1600
    sig_kernel<<<nblocks, TB, 0, stream>>>(x, out, B);
}